// Round 6
// baseline (2231.460 us; speedup 1.0000x reference)
//
#include <hip/hip_runtime.h>
#include <math.h>

#define T_STEPS 32768
#define N_NEUR  1024
#define FILT_LEN 200
#define NSEG    256          // scan segments
#define SEG     128          // steps per segment

typedef float f32x4 __attribute__((ext_vector_type(4)));

__device__ __forceinline__ float waveMax(float v) {
#pragma unroll
    for (int off = 32; off > 0; off >>= 1) v = fmaxf(v, __shfl_xor(v, off));
    return v;
}
__device__ __forceinline__ float waveSum(float v) {
#pragma unroll
    for (int off = 32; off > 0; off >>= 1) v += __shfl_xor(v, off);
    return v;
}
__device__ __forceinline__ int waveSumI(int v) {
#pragma unroll
    for (int off = 32; off > 0; off >>= 1) v += __shfl_xor(v, off);
    return v;
}

// ---------------- noise: 200-tap causal FIR of noise_rand*0.2 ----------------
// NUMERICS FROZEN (passed rounds 2/3/5).
__global__ __launch_bounds__(256) void noise_kernel(
    const float* __restrict__ noise_rand, float* __restrict__ noise_out)
{
    __shared__ float s_filt[FILT_LEN];
    __shared__ float s_nr[256 + FILT_LEN - 1];
    const int tid = threadIdx.x;
    const int t0  = blockIdx.x * 256;

    if (tid < FILT_LEN) s_filt[tid] = expf(-((float)tid * 0.05f));
    for (int i = tid; i < 256 + FILT_LEN - 1; i += 256) {
        int k = t0 - (FILT_LEN - 1) + i;
        s_nr[i] = (k >= 0) ? noise_rand[k] * 0.2f : 0.0f;
    }
    __syncthreads();

    const int t = t0 + tid;
    float acc = 0.0f;
#pragma unroll 4
    for (int j = FILT_LEN - 1; j >= 0; --j) {
        acc = fmaf(s_nr[tid + (FILT_LEN - 1) - j], s_filt[j], acc);
    }
    noise_out[t] = acc;
}

// ---------------- fused rows + sequential scan (producer-consumer) ----------
// Block 0, wave 0: sequential inhibition recurrence (bit-identical per-step
//   numerics to the passing rounds), consuming thr[t] in t-order as the rows
//   blocks publish them (agent-scope release flag per row / acquire poll).
// Blocks 1..8192: rows work, NUMERICS FROZEN from round 5.
// No __syncthreads anywhere (block 0's waves 1-3 exit immediately).
__global__ __launch_bounds__(256) void fused_kernel(
    const float* __restrict__ inputs, const float* __restrict__ noise,
    const float* __restrict__ u_mult, const float* __restrict__ rand_val,
    float* __restrict__ out_spikes, float* __restrict__ inh_out,
    float* __restrict__ thr_ws, int* __restrict__ idx_ws,
    int* __restrict__ flags)
{
    __shared__ float sth[SEG];   // scan segment staging (block 0 wave 0 only)

    if (blockIdx.x == 0) {
        // ---------------- scan wave ----------------
        if (threadIdx.x >= 64) return;
        const int lane = threadIdx.x;
        const float F = 0.8187307530779818f;   // (float)exp(-DT/INH_TAU)
        float inh = 0.0f;

        for (int s = 0; s < NSEG; ++s) {
            const int base = s << 7;           // first t of this segment
            // acquire-poll the 128 producer flags for this segment
            for (;;) {
                int f0 = __hip_atomic_load(&flags[base + lane],
                                           __ATOMIC_ACQUIRE, __HIP_MEMORY_SCOPE_AGENT);
                int f1 = __hip_atomic_load(&flags[base + 64 + lane],
                                           __ATOMIC_ACQUIRE, __HIP_MEMORY_SCOPE_AGENT);
                if (__all(f0 & f1)) break;
                __builtin_amdgcn_s_sleep(2);
            }
            // stage thresholds into LDS (plain loads ordered after acquire)
            sth[lane]      = thr_ws[base + lane];
            sth[64 + lane] = thr_ws[base + 64 + lane];
            // (within-wave LDS write->read; compiler inserts lgkmcnt waits)

            float keep0 = 0.f, keep1 = 0.f;
            bool  sp0 = false, sp1 = false;
#pragma unroll
            for (int i = 0; i < SEG; ++i) {
                float th   = sth[i];               // same addr all lanes: broadcast
                bool spike = inh < th;
                float a = __fmul_rn(inh, F);       // no-spike candidate
                float b = __fadd_rn(a, 3000.0f);   // spike candidate
                inh = spike ? b : a;               // chain: cmp -> cndmask
                if (i < 64) { if (lane == i)      { keep0 = inh; sp0 = spike; } }
                else        { if (lane == i - 64) { keep1 = inh; sp1 = spike; } }
            }
            // coalesced inhibition write-out + sparse one-hot scatter
            inh_out[base + lane]      = keep0;
            inh_out[base + 64 + lane] = keep1;
            if (sp0) out_spikes[(size_t)(base + lane) * N_NEUR
                                + idx_ws[base + lane]] = 1.0f;
            if (sp1) out_spikes[(size_t)(base + 64 + lane) * N_NEUR
                                + idx_ws[base + 64 + lane]] = 1.0f;
        }
        return;
    }

    // ---------------- rows wave (one wave per row; NUMERICS FROZEN) ----------
    const int wid  = threadIdx.x >> 6;
    const int lane = threadIdx.x & 63;
    const int t    = (blockIdx.x - 1) * 4 + wid;

    const f32x4* row = reinterpret_cast<const f32x4*>(inputs + (size_t)t * N_NEUR);
    f32x4 x0 = __builtin_nontemporal_load(&row[lane]);
    f32x4 x1 = __builtin_nontemporal_load(&row[lane + 64]);
    f32x4 x2 = __builtin_nontemporal_load(&row[lane + 128]);
    f32x4 x3 = __builtin_nontemporal_load(&row[lane + 192]);

    // zero-fill this output row BEFORE the flag release (scatter ordered after)
    f32x4 z = (f32x4){0.f, 0.f, 0.f, 0.f};
    f32x4* orow = reinterpret_cast<f32x4*>(out_spikes + (size_t)t * N_NEUR);
    __builtin_nontemporal_store(z, &orow[lane]);
    __builtin_nontemporal_store(z, &orow[lane + 64]);
    __builtin_nontemporal_store(z, &orow[lane + 128]);
    __builtin_nontemporal_store(z, &orow[lane + 192]);

    // ---- row max ----
    float m = fmaxf(
        fmaxf(fmaxf(fmaxf(x0[0], x0[1]), fmaxf(x0[2], x0[3])),
              fmaxf(fmaxf(x1[0], x1[1]), fmaxf(x1[2], x1[3]))),
        fmaxf(fmaxf(fmaxf(x2[0], x2[1]), fmaxf(x2[2], x2[3])),
              fmaxf(fmaxf(x3[0], x3[1]), fmaxf(x3[2], x3[3]))));
    m = waveMax(m);

    // ---- softmax numerators (no noise) + denominator ----
    float e00 = expf(x0[0] - m), e01 = expf(x0[1] - m), e02 = expf(x0[2] - m), e03 = expf(x0[3] - m);
    float e10 = expf(x1[0] - m), e11 = expf(x1[1] - m), e12 = expf(x1[2] - m), e13 = expf(x1[3] - m);
    float e20 = expf(x2[0] - m), e21 = expf(x2[1] - m), e22 = expf(x2[2] - m), e23 = expf(x2[3] - m);
    float e30 = expf(x3[0] - m), e31 = expf(x3[1] - m), e32 = expf(x3[2] - m), e33 = expf(x3[3] - m);
    float s0 = ((e00 + e01) + e02) + e03;
    float s1 = ((e10 + e11) + e12) + e13;
    float s2 = ((e20 + e21) + e22) + e23;
    float s3 = ((e30 + e31) + e32) + e33;
    const float sum_e = waveSum(((s0 + s1) + s2) + s3);

    // ---- logsumexp over y = x + noise; max(y) = fl(m + nz) by monotonicity ----
    const float nz = noise[t];
    const float my = m + nz;
    float f0 = ((expf((x0[0] + nz) - my) + expf((x0[1] + nz) - my))
              +  expf((x0[2] + nz) - my)) + expf((x0[3] + nz) - my);
    float f1 = ((expf((x1[0] + nz) - my) + expf((x1[1] + nz) - my))
              +  expf((x1[2] + nz) - my)) + expf((x1[3] + nz) - my);
    float f2 = ((expf((x2[0] + nz) - my) + expf((x2[1] + nz) - my))
              +  expf((x2[2] + nz) - my)) + expf((x2[3] + nz) - my);
    float f3 = ((expf((x3[0] + nz) - my) + expf((x3[1] + nz) - my))
              +  expf((x3[2] + nz) - my)) + expf((x3[3] + nz) - my);
    const float sum_ey = waveSum(((f0 + f1) + f2) + f3);

    // ---- p = e / sum_e (true division, per reference), hierarchical prefix ----
    float p00 = e00 / sum_e, p01 = e01 / sum_e, p02 = e02 / sum_e, p03 = e03 / sum_e;
    float p10 = e10 / sum_e, p11 = e11 / sum_e, p12 = e12 / sum_e, p13 = e13 / sum_e;
    float p20 = e20 / sum_e, p21 = e21 / sum_e, p22 = e22 / sum_e, p23 = e23 / sum_e;
    float p30 = e30 / sum_e, p31 = e31 / sum_e, p32 = e32 / sum_e, p33 = e33 / sum_e;

    float c00 = p00, c01 = c00 + p01, c02 = c01 + p02, c03 = c02 + p03;
    float c10 = p10, c11 = c10 + p11, c12 = c11 + p12, c13 = c12 + p13;
    float c20 = p20, c21 = c20 + p21, c22 = c21 + p22, c23 = c22 + p23;
    float c30 = p30, c31 = c30 + p31, c32 = c31 + p32, c33 = c32 + p33;

    float g0 = c03, g1 = c13, g2 = c23, g3 = c33;
    float i0 = g0, i1 = g1, i2 = g2, i3 = g3;
#pragma unroll
    for (int off = 1; off < 64; off <<= 1) {
        float v0 = __shfl_up(i0, off), v1 = __shfl_up(i1, off);
        float v2 = __shfl_up(i2, off), v3 = __shfl_up(i3, off);
        if (lane >= off) { i0 += v0; i1 += v1; i2 += v2; i3 += v3; }
    }
    float tot0 = __shfl(i0, 63), tot1 = __shfl(i1, 63), tot2 = __shfl(i2, 63);
    float ex0 = __shfl_up(i0, 1), ex1 = __shfl_up(i1, 1),
          ex2 = __shfl_up(i2, 1), ex3 = __shfl_up(i3, 1);
    if (lane == 0) { ex0 = 0.f; ex1 = 0.f; ex2 = 0.f; ex3 = 0.f; }
    float J1 = tot0, J2 = J1 + tot1, J3 = J2 + tot2;
    float b0 = ex0;
    float b1 = J1 + ex1;
    float b2 = J2 + ex2;
    float b3 = J3 + ex3;

    const float u = u_mult[t];
    int cnt = (int)(b0 + c00 < u) + (int)(b0 + c01 < u) + (int)(b0 + c02 < u) + (int)(b0 + c03 < u)
            + (int)(b1 + c10 < u) + (int)(b1 + c11 < u) + (int)(b1 + c12 < u) + (int)(b1 + c13 < u)
            + (int)(b2 + c20 < u) + (int)(b2 + c21 < u) + (int)(b2 + c22 < u) + (int)(b2 + c23 < u)
            + (int)(b3 + c30 < u) + (int)(b3 + c31 < u) + (int)(b3 + c32 < u) + (int)(b3 + c33 < u);
    cnt = waveSumI(cnt);

    if (lane == 0) {
        int idx = (cnt >= N_NEUR) ? 0 : cnt;   // all-False -> argmax returns 0
        idx_ws[t] = idx;
        float log_total = my + logf(sum_ey);
        thr_ws[t] = (log_total + (float)(-6.907755278982137)) - logf(rand_val[t]);
        // publish: orders ALL this wave's prior stores (zeros, thr, idx)
        __hip_atomic_store(&flags[t], 1, __ATOMIC_RELEASE, __HIP_MEMORY_SCOPE_AGENT);
    }
}

extern "C" void kernel_launch(void* const* d_in, const int* in_sizes, int n_in,
                              void* d_out, int out_size, void* d_ws, size_t ws_size,
                              hipStream_t stream)
{
    const float* inputs     = (const float*)d_in[0];
    const float* noise_rand = (const float*)d_in[1];
    const float* u_mult     = (const float*)d_in[2];
    const float* rand_val   = (const float*)d_in[3];

    float* out_spk   = (float*)d_out;
    float* out_inh   = out_spk + (size_t)T_STEPS * N_NEUR;
    float* out_noise = out_inh + T_STEPS;

    float* thr_ws = (float*)d_ws;
    int*   idx_ws = (int*)((char*)d_ws + (size_t)T_STEPS * 4);
    int*   flags  = (int*)((char*)d_ws + 2 * (size_t)T_STEPS * 4);

    // flags must be zero every call (ws is re-poisoned 0xAA); capture-legal node
    hipMemsetAsync(flags, 0, (size_t)T_STEPS * 4, stream);
    noise_kernel<<<T_STEPS / 256, 256, 0, stream>>>(noise_rand, out_noise);
    fused_kernel<<<T_STEPS / 4 + 1, 256, 0, stream>>>(
        inputs, out_noise, u_mult, rand_val,
        out_spk, out_inh, thr_ws, idx_ws, flags);
}

// Round 7
// 1669.750 us; speedup vs baseline: 1.3364x; 1.3364x over previous
//
#include <hip/hip_runtime.h>
#include <math.h>

#define T_STEPS 32768
#define N_NEUR  1024
#define FILT_LEN 200
#define NMAC    128          // macro-segments of 256 scan steps
#define MSEG    256

typedef float f32x4 __attribute__((ext_vector_type(4)));

__device__ __forceinline__ float waveMax(float v) {
#pragma unroll
    for (int off = 32; off > 0; off >>= 1) v = fmaxf(v, __shfl_xor(v, off));
    return v;
}
__device__ __forceinline__ float waveSum(float v) {
#pragma unroll
    for (int off = 32; off > 0; off >>= 1) v += __shfl_xor(v, off);
    return v;
}
__device__ __forceinline__ int waveSumI(int v) {
#pragma unroll
    for (int off = 32; off > 0; off >>= 1) v += __shfl_xor(v, off);
    return v;
}

// ---------------- noise: 200-tap causal FIR of noise_rand*0.2 ----------------
// NUMERICS FROZEN.
__global__ __launch_bounds__(256) void noise_kernel(
    const float* __restrict__ noise_rand, float* __restrict__ noise_out)
{
    __shared__ float s_filt[FILT_LEN];
    __shared__ float s_nr[256 + FILT_LEN - 1];
    const int tid = threadIdx.x;
    const int t0  = blockIdx.x * 256;

    if (tid < FILT_LEN) s_filt[tid] = expf(-((float)tid * 0.05f));
    for (int i = tid; i < 256 + FILT_LEN - 1; i += 256) {
        int k = t0 - (FILT_LEN - 1) + i;
        s_nr[i] = (k >= 0) ? noise_rand[k] * 0.2f : 0.0f;
    }
    __syncthreads();

    const int t = t0 + tid;
    float acc = 0.0f;
#pragma unroll 4
    for (int j = FILT_LEN - 1; j >= 0; --j) {
        acc = fmaf(s_nr[tid + (FILT_LEN - 1) - j], s_filt[j], acc);
    }
    noise_out[t] = acc;
}

// ---------------- fused rows + sequential scan (producer-consumer) ----------
// thr_ws is pre-memset to NaN (0xFF). Producers release-store the real thr;
// the scan wave (block 0, wave 0) treats non-NaN as "row ready".
__global__ __launch_bounds__(256) void fused_kernel(
    const float* __restrict__ inputs, const float* __restrict__ noise,
    const float* __restrict__ u_mult, const float* __restrict__ rand_val,
    float* __restrict__ out_spikes, float* __restrict__ inh_out,
    float* __restrict__ thr_ws, int* __restrict__ idx_ws)
{
    __shared__ __align__(16) float sth[2][MSEG];   // staged thr, double-buffered
    __shared__ float sring[MSEG];                  // inh ring for post-pass

    if (blockIdx.x == 0) {
        // ================= scan wave =================
        if (threadIdx.x >= 64) return;
        const int lane = threadIdx.x;
        const float F = 0.8187307530779818f;       // (float)exp(-DT/INH_TAU)
        __builtin_amdgcn_s_setprio(1);             // protect the serial chain's issue slots

        f32x4 bk[2][4];                            // two 16-step th banks (regs)
        float inh = 0.0f;
        int ix0, ix1, ix2, ix3;                    // idx prefetch (current seg)
        int jx0 = 0, jx1 = 0, jx2 = 0, jx3 = 0;    // idx prefetch (next seg)

        // ---- STAGE macro-seg 0 ----
        {
            float f0, f1, f2, f3;
            for (;;) {
                f0 = __hip_atomic_load(&thr_ws[4 * lane + 0], __ATOMIC_RELAXED, __HIP_MEMORY_SCOPE_AGENT);
                f1 = __hip_atomic_load(&thr_ws[4 * lane + 1], __ATOMIC_RELAXED, __HIP_MEMORY_SCOPE_AGENT);
                f2 = __hip_atomic_load(&thr_ws[4 * lane + 2], __ATOMIC_RELAXED, __HIP_MEMORY_SCOPE_AGENT);
                f3 = __hip_atomic_load(&thr_ws[4 * lane + 3], __ATOMIC_RELAXED, __HIP_MEMORY_SCOPE_AGENT);
                int ok = (f0 == f0) & (f1 == f1) & (f2 == f2) & (f3 == f3);
                if (__all(ok)) break;
                __builtin_amdgcn_s_sleep(16);
            }
            __builtin_amdgcn_fence(__ATOMIC_ACQUIRE, "agent");
            f32x4 v; v[0] = f0; v[1] = f1; v[2] = f2; v[3] = f3;
            reinterpret_cast<f32x4*>(sth[0])[lane] = v;
            ix0 = idx_ws[lane];       ix1 = idx_ws[64 + lane];
            ix2 = idx_ws[128 + lane]; ix3 = idx_ws[192 + lane];
        }
        // prefetch banks for groups 0,1 of macro-seg 0
        {
            const f32x4* sv = reinterpret_cast<const f32x4*>(sth[0]);
#pragma unroll
            for (int j = 0; j < 4; ++j) bk[0][j] = sv[j];
#pragma unroll
            for (int j = 0; j < 4; ++j) bk[1][j] = sv[4 + j];
        }

        for (int k = 0; k < NMAC; ++k) {
            float* scur = sth[k & 1];
            float* snxt = sth[(k + 1) & 1];
            const int kbase = k << 8;
#pragma unroll
            for (int g = 0; g < 16; ++g) {
                // ---- chain 16 steps on bank bk[g&1] (frozen per-step numerics) ----
#pragma unroll
                for (int i = 0; i < 16; ++i) {
                    float th = bk[g & 1][i >> 2][i & 3];
                    bool spike = inh < th;
                    float a = __fmul_rn(inh, F);        // no-spike candidate
                    float b = __fadd_rn(a, 3000.0f);    // spike candidate
                    inh = spike ? b : a;                // chain: cmp -> cndmask
                    sring[g * 16 + i] = inh;            // same-addr broadcast write
                }
                // ---- prefetch th bank for group g+2 ----
                if (g + 2 < 16) {
                    const f32x4* sv = reinterpret_cast<const f32x4*>(scur);
#pragma unroll
                    for (int j = 0; j < 4; ++j) bk[g & 1][j] = sv[(g + 2) * 4 + j];
                } else if (k + 1 < NMAC) {
                    const f32x4* sv = reinterpret_cast<const f32x4*>(snxt);
#pragma unroll
                    for (int j = 0; j < 4; ++j) bk[g & 1][j] = sv[(g + 2 - 16) * 4 + j];
                }
                // ---- stage next macro-seg (early, hidden under chain) ----
                if (g == 2 && k + 1 < NMAC) {
                    const int nb = (k + 1) << 8;
                    float f0, f1, f2, f3;
                    for (;;) {
                        f0 = __hip_atomic_load(&thr_ws[nb + 4 * lane + 0], __ATOMIC_RELAXED, __HIP_MEMORY_SCOPE_AGENT);
                        f1 = __hip_atomic_load(&thr_ws[nb + 4 * lane + 1], __ATOMIC_RELAXED, __HIP_MEMORY_SCOPE_AGENT);
                        f2 = __hip_atomic_load(&thr_ws[nb + 4 * lane + 2], __ATOMIC_RELAXED, __HIP_MEMORY_SCOPE_AGENT);
                        f3 = __hip_atomic_load(&thr_ws[nb + 4 * lane + 3], __ATOMIC_RELAXED, __HIP_MEMORY_SCOPE_AGENT);
                        int ok = (f0 == f0) & (f1 == f1) & (f2 == f2) & (f3 == f3);
                        if (__all(ok)) break;
                        __builtin_amdgcn_s_sleep(16);
                    }
                    __builtin_amdgcn_fence(__ATOMIC_ACQUIRE, "agent");
                    f32x4 v; v[0] = f0; v[1] = f1; v[2] = f2; v[3] = f3;
                    reinterpret_cast<f32x4*>(snxt)[lane] = v;
                    jx0 = idx_ws[nb + lane];       jx1 = idx_ws[nb + 64 + lane];
                    jx2 = idx_ws[nb + 128 + lane]; jx3 = idx_ws[nb + 192 + lane];
                }
            }
            // ---- post-pass: write inh, scatter spikes (spike <=> inh' >= 2500;
            //      post-spike >= 3000, max no-spike <= 3014*F = 2468) ----
            float v0 = sring[lane],       v1 = sring[64 + lane];
            float v2 = sring[128 + lane], v3 = sring[192 + lane];
            inh_out[kbase + lane]       = v0;
            inh_out[kbase + 64 + lane]  = v1;
            inh_out[kbase + 128 + lane] = v2;
            inh_out[kbase + 192 + lane] = v3;
            if (v0 >= 2500.0f) out_spikes[(size_t)(kbase + lane)       * N_NEUR + ix0] = 1.0f;
            if (v1 >= 2500.0f) out_spikes[(size_t)(kbase + 64 + lane)  * N_NEUR + ix1] = 1.0f;
            if (v2 >= 2500.0f) out_spikes[(size_t)(kbase + 128 + lane) * N_NEUR + ix2] = 1.0f;
            if (v3 >= 2500.0f) out_spikes[(size_t)(kbase + 192 + lane) * N_NEUR + ix3] = 1.0f;
            ix0 = jx0; ix1 = jx1; ix2 = jx2; ix3 = jx3;
        }
        return;
    }

    // ================= rows wave (one wave per row; NUMERICS FROZEN) =========
    const int wid  = threadIdx.x >> 6;
    const int lane = threadIdx.x & 63;
    const int t    = (blockIdx.x - 1) * 4 + wid;

    const f32x4* row = reinterpret_cast<const f32x4*>(inputs + (size_t)t * N_NEUR);
    f32x4 x0 = __builtin_nontemporal_load(&row[lane]);
    f32x4 x1 = __builtin_nontemporal_load(&row[lane + 64]);
    f32x4 x2 = __builtin_nontemporal_load(&row[lane + 128]);
    f32x4 x3 = __builtin_nontemporal_load(&row[lane + 192]);

    // zero-fill this output row BEFORE the release (scatter ordered after it)
    f32x4 z = (f32x4){0.f, 0.f, 0.f, 0.f};
    f32x4* orow = reinterpret_cast<f32x4*>(out_spikes + (size_t)t * N_NEUR);
    __builtin_nontemporal_store(z, &orow[lane]);
    __builtin_nontemporal_store(z, &orow[lane + 64]);
    __builtin_nontemporal_store(z, &orow[lane + 128]);
    __builtin_nontemporal_store(z, &orow[lane + 192]);

    // ---- row max ----
    float m = fmaxf(
        fmaxf(fmaxf(fmaxf(x0[0], x0[1]), fmaxf(x0[2], x0[3])),
              fmaxf(fmaxf(x1[0], x1[1]), fmaxf(x1[2], x1[3]))),
        fmaxf(fmaxf(fmaxf(x2[0], x2[1]), fmaxf(x2[2], x2[3])),
              fmaxf(fmaxf(x3[0], x3[1]), fmaxf(x3[2], x3[3]))));
    m = waveMax(m);

    // ---- softmax numerators (no noise) + denominator ----
    float e00 = expf(x0[0] - m), e01 = expf(x0[1] - m), e02 = expf(x0[2] - m), e03 = expf(x0[3] - m);
    float e10 = expf(x1[0] - m), e11 = expf(x1[1] - m), e12 = expf(x1[2] - m), e13 = expf(x1[3] - m);
    float e20 = expf(x2[0] - m), e21 = expf(x2[1] - m), e22 = expf(x2[2] - m), e23 = expf(x2[3] - m);
    float e30 = expf(x3[0] - m), e31 = expf(x3[1] - m), e32 = expf(x3[2] - m), e33 = expf(x3[3] - m);
    float s0 = ((e00 + e01) + e02) + e03;
    float s1 = ((e10 + e11) + e12) + e13;
    float s2 = ((e20 + e21) + e22) + e23;
    float s3 = ((e30 + e31) + e32) + e33;
    const float sum_e = waveSum(((s0 + s1) + s2) + s3);

    // ---- logsumexp over y = x + noise; max(y) = fl(m + nz) by monotonicity ----
    const float nz = noise[t];
    const float my = m + nz;
    float f0 = ((expf((x0[0] + nz) - my) + expf((x0[1] + nz) - my))
              +  expf((x0[2] + nz) - my)) + expf((x0[3] + nz) - my);
    float f1 = ((expf((x1[0] + nz) - my) + expf((x1[1] + nz) - my))
              +  expf((x1[2] + nz) - my)) + expf((x1[3] + nz) - my);
    float f2 = ((expf((x2[0] + nz) - my) + expf((x2[1] + nz) - my))
              +  expf((x2[2] + nz) - my)) + expf((x2[3] + nz) - my);
    float f3 = ((expf((x3[0] + nz) - my) + expf((x3[1] + nz) - my))
              +  expf((x3[2] + nz) - my)) + expf((x3[3] + nz) - my);
    const float sum_ey = waveSum(((f0 + f1) + f2) + f3);

    // ---- p = e / sum_e (true division, per reference), hierarchical prefix ----
    float p00 = e00 / sum_e, p01 = e01 / sum_e, p02 = e02 / sum_e, p03 = e03 / sum_e;
    float p10 = e10 / sum_e, p11 = e11 / sum_e, p12 = e12 / sum_e, p13 = e13 / sum_e;
    float p20 = e20 / sum_e, p21 = e21 / sum_e, p22 = e22 / sum_e, p23 = e23 / sum_e;
    float p30 = e30 / sum_e, p31 = e31 / sum_e, p32 = e32 / sum_e, p33 = e33 / sum_e;

    float c00 = p00, c01 = c00 + p01, c02 = c01 + p02, c03 = c02 + p03;
    float c10 = p10, c11 = c10 + p11, c12 = c11 + p12, c13 = c12 + p13;
    float c20 = p20, c21 = c20 + p21, c22 = c21 + p22, c23 = c22 + p23;
    float c30 = p30, c31 = c30 + p31, c32 = c31 + p32, c33 = c32 + p33;

    float g0 = c03, g1 = c13, g2 = c23, g3 = c33;
    float i0 = g0, i1 = g1, i2 = g2, i3 = g3;
#pragma unroll
    for (int off = 1; off < 64; off <<= 1) {
        float v0 = __shfl_up(i0, off), v1 = __shfl_up(i1, off);
        float v2 = __shfl_up(i2, off), v3 = __shfl_up(i3, off);
        if (lane >= off) { i0 += v0; i1 += v1; i2 += v2; i3 += v3; }
    }
    float tot0 = __shfl(i0, 63), tot1 = __shfl(i1, 63), tot2 = __shfl(i2, 63);
    float ex0 = __shfl_up(i0, 1), ex1 = __shfl_up(i1, 1),
          ex2 = __shfl_up(i2, 1), ex3 = __shfl_up(i3, 1);
    if (lane == 0) { ex0 = 0.f; ex1 = 0.f; ex2 = 0.f; ex3 = 0.f; }
    float J1 = tot0, J2 = J1 + tot1, J3 = J2 + tot2;
    float b0 = ex0;
    float b1 = J1 + ex1;
    float b2 = J2 + ex2;
    float b3 = J3 + ex3;

    const float u = u_mult[t];
    int cnt = (int)(b0 + c00 < u) + (int)(b0 + c01 < u) + (int)(b0 + c02 < u) + (int)(b0 + c03 < u)
            + (int)(b1 + c10 < u) + (int)(b1 + c11 < u) + (int)(b1 + c12 < u) + (int)(b1 + c13 < u)
            + (int)(b2 + c20 < u) + (int)(b2 + c21 < u) + (int)(b2 + c22 < u) + (int)(b2 + c23 < u)
            + (int)(b3 + c30 < u) + (int)(b3 + c31 < u) + (int)(b3 + c32 < u) + (int)(b3 + c33 < u);
    cnt = waveSumI(cnt);

    if (lane == 0) {
        int idx = (cnt >= N_NEUR) ? 0 : cnt;   // all-False -> argmax returns 0
        idx_ws[t] = idx;
        float log_total = my + logf(sum_ey);
        float thrv = (log_total + (float)(-6.907755278982137)) - logf(rand_val[t]);
        // release publish: orders zero-fill + idx store before thr becomes non-NaN
        __hip_atomic_store(&thr_ws[t], thrv, __ATOMIC_RELEASE, __HIP_MEMORY_SCOPE_AGENT);
    }
}

extern "C" void kernel_launch(void* const* d_in, const int* in_sizes, int n_in,
                              void* d_out, int out_size, void* d_ws, size_t ws_size,
                              hipStream_t stream)
{
    const float* inputs     = (const float*)d_in[0];
    const float* noise_rand = (const float*)d_in[1];
    const float* u_mult     = (const float*)d_in[2];
    const float* rand_val   = (const float*)d_in[3];

    float* out_spk   = (float*)d_out;
    float* out_inh   = out_spk + (size_t)T_STEPS * N_NEUR;
    float* out_noise = out_inh + T_STEPS;

    float* thr_ws = (float*)d_ws;
    int*   idx_ws = (int*)((char*)d_ws + (size_t)T_STEPS * 4);

    // thr sentinel = NaN (0xFF bytes); rows overwrite with real (finite) thr
    hipMemsetAsync(thr_ws, 0xFF, (size_t)T_STEPS * 4, stream);
    noise_kernel<<<T_STEPS / 256, 256, 0, stream>>>(noise_rand, out_noise);
    fused_kernel<<<T_STEPS / 4 + 1, 256, 0, stream>>>(
        inputs, out_noise, u_mult, rand_val,
        out_spk, out_inh, thr_ws, idx_ws);
}